// Round 10
// baseline (587.956 us; speedup 1.0000x reference)
//
#include <hip/hip_runtime.h>
#include <math.h>

#define Q 256

typedef unsigned short u16;
typedef unsigned int u32;
typedef __attribute__((ext_vector_type(8))) short short8;
typedef __attribute__((ext_vector_type(4))) float f32x4;

__device__ __forceinline__ float bf2f(u32 u){
  union { float f; u32 i; } v; v.i = u << 16; return v.f;
}
__device__ __forceinline__ u16 f2bf(float f){
  union { float f; u32 i; } v; v.f = f;
  u32 r = (v.i + 0x7FFFu + ((v.i >> 16) & 1u)) >> 16;
  return (u16)r;
}
__device__ __forceinline__ float softplusf(float x){
  return x > 20.f ? x : log1pf(expf(x));
}
__device__ __forceinline__ float siluf(float x){
  return x / (1.f + expf(-x));
}

__device__ __forceinline__ void gload_lds16(const void* g, const void* l){
  __builtin_amdgcn_global_load_lds(
    (const __attribute__((address_space(1))) void*)(uintptr_t)g,
    (__attribute__((address_space(3))) void*)(u32)(uintptr_t)l,
    16, 0, 0);
}

__device__ __forceinline__ u32 swz_off(int row, int col2){
  return (u32)(row*128 + (col2 ^ ((row & 7) << 4)));
}
__device__ __forceinline__ short8 frag_ld(const u16* buf, int row, int kk, int lk){
  return *(const short8*)((const char*)buf + row*128 + (((kk*4 + lk) ^ (row & 7)) << 4));
}

__global__ __launch_bounds__(256) void cast_bf16(const float* __restrict__ in,
    u16* __restrict__ out)
{
  const size_t i = ((size_t)blockIdx.x * 256 + threadIdx.x) * 4;
  const float4 v = *(const float4*)(in + i);
  ushort4 o;
  o.x = f2bf(v.x); o.y = f2bf(v.y); o.z = f2bf(v.z); o.w = f2bf(v.w);
  *(ushort4*)(out + i) = o;
}

// ------------- 256x256 MFMA core: 8-phase schedule, ring-4 K-32 slots ------
// 512 thr = 8 waves (2M x 4N); per-wave output 128x64. Slot (32 KiB) =
// 256 rows x 128 B = one K-slice-32 (A chunks 0-3, B chunks 4-7, phys chunk
// = logical ^ (row&7)); gload_lds linear dest, pre-swizzled source (rule #21).
// Per slice j, TWO phases of 16 MFMA (m-half 0 / m-half 1):
//   even: vmgate(j) ; rd B(j)[4] + A(j,mh0)[4] ; stage slice j+3 ;
//         barrier ; lgkm(0) ; setprio(1) 16 MFMA setprio(0) ; barrier
//   odd:  rd A(j,mh1)[4] ; barrier ; lgkm(0) ; 16 MFMA ; barrier
// vmgate = counted vmcnt(8): outstanding = slices {j,j+1,j+2} (12 loads) ->
// retires j, keeps 8 in flight across barriers (never drains; tail 4/0).
// WAR: stage(j+3) hits ring slot (j-1)&3; slice j-1's reads retired at its
// odd-phase lgkm(0) + closing barrier, which precede this stage.
#define G8_STAGE(s_) \
  _Pragma("unroll") for (int q = 0; q < 4; q++) \
    gload_lds16(sptr[q] + (s_)*32, lds + (((s_)&3)*32768) + (q*512 + tid)*16);

#define G8_MFMA16(mh_) \
  __builtin_amdgcn_s_barrier(); \
  asm volatile("s_waitcnt lgkmcnt(0)" ::: "memory"); \
  __builtin_amdgcn_sched_barrier(0); \
  __builtin_amdgcn_s_setprio(1); \
  _Pragma("unroll") for (int m = 0; m < 4; m++) \
  _Pragma("unroll") for (int n = 0; n < 4; n++) \
    acc[(mh_)*4+m][n] = __builtin_amdgcn_mfma_f32_16x16x32_bf16(aF[m], bF[n], acc[(mh_)*4+m][n], 0, 0, 0); \
  __builtin_amdgcn_s_setprio(0); \
  __builtin_amdgcn_s_barrier();

#define G8_CORE(A_, B_, K_, NTN_) \
  extern __shared__ char lds[]; \
  const int tid = threadIdx.x; \
  const int nwg = gridDim.x, bid = blockIdx.x; \
  const int wg = (bid & 7) * (nwg >> 3) + (bid >> 3); \
  const int m0 = (wg / (NTN_)) * 256, n0 = (wg % (NTN_)) * 256; \
  const int w = tid >> 6, l = tid & 63; \
  const int wr = w >> 2, wc = w & 3; \
  const int lr = l & 15, lk = l >> 4; \
  const u16* sptr[4]; \
  _Pragma("unroll") for (int q = 0; q < 4; q++) { \
    const int c = q*512 + tid; \
    const int r = c >> 3; \
    const int jl = (c & 7) ^ (r & 7); \
    sptr[q] = (jl < 4) ? ((A_) + (size_t)(m0 + r)*(K_) + jl*8) \
                       : ((B_) + (size_t)(n0 + r)*(K_) + (jl-4)*8); \
  } \
  const int abase0 = (wr*128 + lr)*128 + ((lk ^ (lr & 7)) << 4); \
  const int bbase0 = (wc*64  + lr)*128 + (((4 + lk) ^ (lr & 7)) << 4); \
  f32x4 acc[8][4]; \
  { f32x4 z = {0.f,0.f,0.f,0.f}; \
    _Pragma("unroll") for (int m = 0; m < 8; m++) \
    _Pragma("unroll") for (int n = 0; n < 4; n++) acc[m][n] = z; } \
  short8 aF[4], bF[4]; \
  G8_STAGE(0) G8_STAGE(1) G8_STAGE(2) \
  asm volatile("s_waitcnt vmcnt(8)" ::: "memory"); \
  __builtin_amdgcn_s_barrier(); \
  { const int NS = (K_)/32; \
    for (int j = 0; j < NS; ++j) { \
      const char* sb_ = lds + ((j & 3)*32768); \
      /* even phase (m-half 0) */ \
      if (j < NS-2)       { asm volatile("s_waitcnt vmcnt(8)" ::: "memory"); } \
      else if (j == NS-2) { asm volatile("s_waitcnt vmcnt(4)" ::: "memory"); } \
      else                { asm volatile("s_waitcnt vmcnt(0)" ::: "memory"); } \
      _Pragma("unroll") for (int n = 0; n < 4; n++) \
        bF[n] = *(const short8*)(sb_ + bbase0 + n*2048); \
      _Pragma("unroll") for (int m = 0; m < 4; m++) \
        aF[m] = *(const short8*)(sb_ + abase0 + m*2048); \
      if (j + 3 < NS) { G8_STAGE(j+3) } \
      G8_MFMA16(0) \
      /* odd phase (m-half 1) */ \
      _Pragma("unroll") for (int m = 0; m < 4; m++) \
        aF[m] = *(const short8*)(sb_ + abase0 + 8192 + m*2048); \
      G8_MFMA16(1) \
    } \
  }

__global__ void __launch_bounds__(512, 2) gemm_in256(const u16* __restrict__ A,
    const u16* __restrict__ B, u16* __restrict__ inp, u16* __restrict__ resb)
{
  G8_CORE(A, B, 2048, 32)
  #pragma unroll
  for (int m = 0; m < 8; m++)
    #pragma unroll
    for (int n = 0; n < 4; n++) {
      const int col = n0 + wc*64 + n*16 + lr;
      #pragma unroll
      for (int j = 0; j < 4; j++) {
        const int row = m0 + wr*128 + m*16 + lk*4 + j;
        const u16 v = f2bf(acc[m][n][j]);
        if (col < 4096) inp[(size_t)row*4096 + col] = v;
        else            resb[(size_t)row*4096 + (col - 4096)] = v;
      }
    }
}

__global__ void __launch_bounds__(512, 2) gemm_par256(const u16* __restrict__ A,
    const u16* __restrict__ B, float* __restrict__ dtb,
    u16* __restrict__ Bb, u16* __restrict__ Cb)
{
  G8_CORE(A, B, 2048, 33)
  #pragma unroll
  for (int m = 0; m < 8; m++)
    #pragma unroll
    for (int n = 0; n < 4; n++) {
      const int col = n0 + wc*64 + n*16 + lr;
      if (col < 8256) {
        const int h = col / 129, rr = col - h*129;
        #pragma unroll
        for (int j = 0; j < 4; j++) {
          const int row = m0 + wr*128 + m*16 + lk*4 + j;
          const float v = acc[m][n][j];
          if (rr == 0)      dtb[(size_t)row*64 + h] = v;
          else if (rr < 65) Bb[((size_t)row*64 + h)*64 + (rr-1)]  = f2bf(v);
          else              Cb[((size_t)row*64 + h)*64 + (rr-65)] = f2bf(v);
        }
      }
    }
}

// ---------------- old 128x128 core (kept for gemm_out) ----------------------
#define MFMA_GEMM_CORE(Abf_, Bbf_, K_) \
  __shared__ short As[128*64]; \
  __shared__ short Bs[128*64]; \
  const int tid = threadIdx.x; \
  const int w = tid >> 6, l = tid & 63; \
  const int m0 = blockIdx.y * 128, n0 = blockIdx.x * 128; \
  const int wr = (w >> 1) * 64, wc = (w & 1) * 64; \
  const int sub = l >> 3; \
  const int scol = ((l & 7) ^ sub) * 8; \
  const int lr16 = l & 15; \
  const int koff = (l >> 4) << 4; \
  const int swz = (l & 7) << 4; \
  f32x4 acc[4][4]; \
  { f32x4 z = {0.f, 0.f, 0.f, 0.f}; \
    _Pragma("unroll") for (int m_ = 0; m_ < 4; m_++) \
    _Pragma("unroll") for (int n_ = 0; n_ < 4; n_++) acc[m_][n_] = z; } \
  const u16* Agp = (Abf_) + (size_t)m0 * (K_); \
  const u16* Bgp = (Bbf_) + (size_t)n0 * (K_); \
  for (int kt = 0; kt < (K_); kt += 64) { \
    __syncthreads(); \
    _Pragma("unroll") for (int i_ = 0; i_ < 4; i_++) { \
      const int rbase = i_*32 + w*8; \
      gload_lds16(Agp + (size_t)(rbase + sub)*(K_) + kt + scol, As + rbase*64); \
      gload_lds16(Bgp + (size_t)(rbase + sub)*(K_) + kt + scol, Bs + rbase*64); \
    } \
    __syncthreads(); \
    short8 af[2][4], bf[2][4]; \
    _Pragma("unroll") for (int kk = 0; kk < 2; kk++) { \
      _Pragma("unroll") for (int m_ = 0; m_ < 4; m_++) \
        af[kk][m_] = *(const short8*)((const char*)As + (wr + m_*16 + lr16)*128 + ((kk*64 + koff) ^ swz)); \
      _Pragma("unroll") for (int n_ = 0; n_ < 4; n_++) \
        bf[kk][n_] = *(const short8*)((const char*)Bs + (wc + n_*16 + lr16)*128 + ((kk*64 + koff) ^ swz)); \
    } \
    _Pragma("unroll") for (int m_ = 0; m_ < 4; m_++) \
    _Pragma("unroll") for (int n_ = 0; n_ < 4; n_++) \
    _Pragma("unroll") for (int kk = 0; kk < 2; kk++) \
      acc[m_][n_] = __builtin_amdgcn_mfma_f32_16x16x32_bf16(af[kk][m_], bf[kk][n_], acc[m_][n_], 0, 0, 0); \
  } \
  const int orow0 = m0 + wr + ((l >> 4) << 2); \
  const int ocol0 = n0 + wc + (l & 15);

__global__ __launch_bounds__(256) void gemm_out(const u16* __restrict__ A,
    const u16* __restrict__ B, float* __restrict__ C)
{
  MFMA_GEMM_CORE(A, B, 4096)
  #pragma unroll
  for (int m_ = 0; m_ < 4; m_++)
    #pragma unroll
    for (int n_ = 0; n_ < 4; n_++) {
      const int col = ocol0 + n_*16;
      #pragma unroll
      for (int j = 0; j < 4; j++)
        C[(size_t)(orow0 + m_*16 + j)*2048 + col] = acc[m_][n_][j];
    }
}

// ---------------- SSD ------------------------------------------------------
__global__ __launch_bounds__(256) void ssd_phaseA(const float* __restrict__ dtb,
    const u16* __restrict__ Bb, const u16* __restrict__ inp,
    float* __restrict__ cs_g, float* __restrict__ achunk, float* __restrict__ states_t)
{
  const int g = blockIdx.x, tid = threadIdx.x;
  const int p = g * Q + tid;
  __shared__ float sc[Q];
  __shared__ u16 sBt[64*64];
  __shared__ u16 sXt[64*64];
  sc[tid] = -softplusf(dtb[p]);
  __syncthreads();
  for (int off = 1; off < Q; off <<= 1) {
    float v = (tid >= off) ? sc[tid - off] : 0.f;
    __syncthreads();
    if (tid >= off) sc[tid] += v;
    __syncthreads();
  }
  cs_g[p] = sc[tid];
  const float cl = sc[Q-1];
  if (tid == 0) achunk[g] = expf(cl);

  const int w = tid >> 6, l = tid & 63;
  const int lrow = l & 15, lk = l >> 4;
  const int tj = tid & 63, tcb = (tid >> 6) * 16;
  f32x4 acc[4];
  { f32x4 z = {0,0,0,0}; acc[0]=z; acc[1]=z; acc[2]=z; acc[3]=z; }

  for (int js = 0; js < 4; js++) {
    __syncthreads();
    {
      const int jc = js*64 + tj;
      const float wj = expf(cl - sc[jc]);
      const size_t prow = ((size_t)g*Q + jc) * 64;
      union { uint4 v; u16 s[8]; } b0, b1, x0, x1;
      b0.v = *(const uint4*)&Bb[prow + tcb];
      b1.v = *(const uint4*)&Bb[prow + tcb + 8];
      x0.v = *(const uint4*)&inp[prow + tcb];
      x1.v = *(const uint4*)&inp[prow + tcb + 8];
      #pragma unroll
      for (int q = 0; q < 8; q++) {
        const int r0 = tcb + q, r1 = tcb + 8 + q;
        *(u16*)((char*)sBt + swz_off(r0, 2*tj)) = f2bf(wj * bf2f((u32)b0.s[q]));
        *(u16*)((char*)sBt + swz_off(r1, 2*tj)) = f2bf(wj * bf2f((u32)b1.s[q]));
        *(u16*)((char*)sXt + swz_off(r0, 2*tj)) = x0.s[q];
        *(u16*)((char*)sXt + swz_off(r1, 2*tj)) = x1.s[q];
      }
    }
    __syncthreads();
    short8 aX0 = frag_ld(sXt, w*16 + lrow, 0, lk);
    short8 aX1 = frag_ld(sXt, w*16 + lrow, 1, lk);
    #pragma unroll
    for (int n = 0; n < 4; n++) {
      short8 b0 = frag_ld(sBt, n*16 + lrow, 0, lk);
      short8 b1 = frag_ld(sBt, n*16 + lrow, 1, lk);
      acc[n] = __builtin_amdgcn_mfma_f32_16x16x32_bf16(aX0, b0, acc[n], 0, 0, 0);
      acc[n] = __builtin_amdgcn_mfma_f32_16x16x32_bf16(aX1, b1, acc[n], 0, 0, 0);
    }
  }
  #pragma unroll
  for (int reg = 0; reg < 4; reg++) {
    const int d = w*16 + lk*4 + reg;
    #pragma unroll
    for (int n = 0; n < 4; n++)
      states_t[(size_t)g*4096 + d*64 + n*16 + lrow] = acc[n][reg];
  }
}

__global__ __launch_bounds__(256) void ssd_scan(float* __restrict__ states,
    const float* __restrict__ achunk)
{
  const int n = blockIdx.x, tid = threadIdx.x;
  float S[16];
  #pragma unroll
  for (int k = 0; k < 16; k++) S[k] = 0.f;
  for (int c = 0; c < 16; c++) {
    const int g = n*16 + c;
    const float A = achunk[g];
    #pragma unroll
    for (int k = 0; k < 16; k++) {
      const size_t e = (size_t)g * 4096 + tid + k*256;
      const float st = states[e];
      states[e] = S[k];
      S[k] = fmaf(A, S[k], st);
    }
  }
}

__global__ __launch_bounds__(256) void ssd_diag(const u16* __restrict__ Bb,
    const u16* __restrict__ Cb, const u16* __restrict__ inp,
    const float* __restrict__ cs_g, const float* __restrict__ states_t,
    const u16* __restrict__ resb, u16* __restrict__ yb)
{
  const int g = blockIdx.y, it = blockIdx.x, tid = threadIdx.x;
  const int w = tid >> 6, l = tid & 63;
  const int lrow = l & 15, lk = l >> 4;
  const int p_base = g * Q;
  __shared__ u16 sC[64*64];
  __shared__ u16 sB[64*64];
  __shared__ u16 sX[64*64];
  __shared__ u16 sP[64*64];
  __shared__ float csi[64], csj[64];

  const int r = tid >> 2, c0 = (tid & 3) << 4;
  {
    const size_t prow = (size_t)(p_base + it*64 + r) * 64;
    uint4 v0 = *(const uint4*)&Cb[prow + c0];
    uint4 v1 = *(const uint4*)&Cb[prow + c0 + 8];
    *(uint4*)((char*)sC + swz_off(r, c0*2))      = v0;
    *(uint4*)((char*)sC + swz_off(r, c0*2 + 16)) = v1;
    if (tid < 64) csi[tid] = cs_g[p_base + it*64 + tid];
  }
  const int i0 = w * 16;
  const int xj = tid & 63, xdb = (tid >> 6) * 16;
  f32x4 accY[4];
  { f32x4 z = {0,0,0,0}; accY[0]=z; accY[1]=z; accY[2]=z; accY[3]=z; }

  for (int jt = 0; jt <= it; jt++) {
    __syncthreads();
    {
      const size_t prow = (size_t)(p_base + jt*64 + r) * 64;
      uint4 v0 = *(const uint4*)&Bb[prow + c0];
      uint4 v1 = *(const uint4*)&Bb[prow + c0 + 8];
      *(uint4*)((char*)sB + swz_off(r, c0*2))      = v0;
      *(uint4*)((char*)sB + swz_off(r, c0*2 + 16)) = v1;
      if (tid < 64) csj[tid] = cs_g[p_base + jt*64 + tid];
    }
    {
      const size_t prow = (size_t)(p_base + jt*64 + xj) * 64;
      union { uint4 v; u16 s[8]; } x0, x1;
      x0.v = *(const uint4*)&inp[prow + xdb];
      x1.v = *(const uint4*)&inp[prow + xdb + 8];
      #pragma unroll
      for (int q = 0; q < 8; q++) {
        *(u16*)((char*)sX + swz_off(xdb + q,     2*xj)) = x0.s[q];
        *(u16*)((char*)sX + swz_off(xdb + 8 + q, 2*xj)) = x1.s[q];
      }
    }
    __syncthreads();
    f32x4 sAcc[4];
    { f32x4 z = {0,0,0,0}; sAcc[0]=z; sAcc[1]=z; sAcc[2]=z; sAcc[3]=z; }
    {
      short8 aC0 = frag_ld(sC, i0 + lrow, 0, lk);
      short8 aC1 = frag_ld(sC, i0 + lrow, 1, lk);
      #pragma unroll
      for (int n = 0; n < 4; n++) {
        short8 b0 = frag_ld(sB, n*16 + lrow, 0, lk);
        short8 b1 = frag_ld(sB, n*16 + lrow, 1, lk);
        sAcc[n] = __builtin_amdgcn_mfma_f32_16x16x32_bf16(aC0, b0, sAcc[n], 0, 0, 0);
        sAcc[n] = __builtin_amdgcn_mfma_f32_16x16x32_bf16(aC1, b1, sAcc[n], 0, 0, 0);
      }
    }
    const bool full = (jt < it);
    #pragma unroll
    for (int n = 0; n < 4; n++) {
      const int j_l = n*16 + lrow;
      const float cj = csj[j_l];
      #pragma unroll
      for (int reg = 0; reg < 4; reg++) {
        const int i_l = i0 + lk*4 + reg;
        float s = 0.f;
        if (full || j_l <= i_l) s = sAcc[n][reg] * expf(csi[i_l] - cj);
        *(u16*)((char*)sP + swz_off(i_l, n*32 + 2*lrow)) = f2bf(s);
      }
    }
    {
      short8 aP0 = frag_ld(sP, i0 + lrow, 0, lk);
      short8 aP1 = frag_ld(sP, i0 + lrow, 1, lk);
      #pragma unroll
      for (int n = 0; n < 4; n++) {
        short8 x0f = frag_ld(sX, n*16 + lrow, 0, lk);
        short8 x1f = frag_ld(sX, n*16 + lrow, 1, lk);
        accY[n] = __builtin_amdgcn_mfma_f32_16x16x32_bf16(aP0, x0f, accY[n], 0, 0, 0);
        accY[n] = __builtin_amdgcn_mfma_f32_16x16x32_bf16(aP1, x1f, accY[n], 0, 0, 0);
      }
    }
  }
  __syncthreads();
  {
    const int d = tid & 63, sb = (tid >> 6) * 16;
    const float* srow = &states_t[(size_t)g*4096 + d*64 + sb];
    float4 f0 = *(const float4*)(srow);
    float4 f1 = *(const float4*)(srow + 4);
    float4 f2 = *(const float4*)(srow + 8);
    float4 f3 = *(const float4*)(srow + 12);
    union { uint4 v; u16 s[8]; } o0, o1;
    o0.s[0]=f2bf(f0.x); o0.s[1]=f2bf(f0.y); o0.s[2]=f2bf(f0.z); o0.s[3]=f2bf(f0.w);
    o0.s[4]=f2bf(f1.x); o0.s[5]=f2bf(f1.y); o0.s[6]=f2bf(f1.z); o0.s[7]=f2bf(f1.w);
    o1.s[0]=f2bf(f2.x); o1.s[1]=f2bf(f2.y); o1.s[2]=f2bf(f2.z); o1.s[3]=f2bf(f2.w);
    o1.s[4]=f2bf(f3.x); o1.s[5]=f2bf(f3.y); o1.s[6]=f2bf(f3.z); o1.s[7]=f2bf(f3.w);
    *(uint4*)((char*)sB + swz_off(d, sb*2))      = o0.v;
    *(uint4*)((char*)sB + swz_off(d, sb*2 + 16)) = o1.v;
  }
  __syncthreads();
  f32x4 accI[4];
  { f32x4 z = {0,0,0,0}; accI[0]=z; accI[1]=z; accI[2]=z; accI[3]=z; }
  {
    short8 aC0 = frag_ld(sC, i0 + lrow, 0, lk);
    short8 aC1 = frag_ld(sC, i0 + lrow, 1, lk);
    #pragma unroll
    for (int n = 0; n < 4; n++) {
      short8 s0 = frag_ld(sB, n*16 + lrow, 0, lk);
      short8 s1 = frag_ld(sB, n*16 + lrow, 1, lk);
      accI[n] = __builtin_amdgcn_mfma_f32_16x16x32_bf16(aC0, s0, accI[n], 0, 0, 0);
      accI[n] = __builtin_amdgcn_mfma_f32_16x16x32_bf16(aC1, s1, accI[n], 0, 0, 0);
    }
  }
  #pragma unroll
  for (int reg = 0; reg < 4; reg++) {
    const int i_l = i0 + lk*4 + reg;
    const float ei = expf(csi[i_l]);
    const size_t prow = (size_t)(p_base + it*64 + i_l) * 64;
    #pragma unroll
    for (int n = 0; n < 4; n++) {
      const int d = n*16 + lrow;
      const float yv = accY[n][reg] + ei * accI[n][reg];
      const float rv = bf2f((u32)resb[prow + d]);
      yb[prow + d] = f2bf(yv * siluf(rv));
    }
  }
}

extern "C" void kernel_launch(void* const* d_in, const int* in_sizes, int n_in,
                              void* d_out, int out_size, void* d_ws, size_t ws_size,
                              hipStream_t stream)
{
  const float* x       = (const float*)d_in[0];
  const float* w_in    = (const float*)d_in[1];
  const float* w_param = (const float*)d_in[2];
  const float* w_out   = (const float*)d_in[3];
  float* out = (float*)d_out;
  char* ws = (char*)d_ws;

  float* states    = (float*)(ws);                 // 16 MiB (aliases xb)
  u16*   xb        = (u16*)  (ws);                 // 16 MiB
  u16*   yb        = (u16*)  (ws + 0x1000000ull);  // 32 MiB (aliases w_in_b)
  u16*   w_in_b    = (u16*)  (ws + 0x1000000ull);  // 32 MiB
  u16*   w_param_b = (u16*)  (ws + 0x3000000ull);  // 8448*2048*2 = 33 MiB (pad rows)
  u16*   w_out_b   = (u16*)  (ws + 0x5100000ull);  // 16 MiB
  u16*   inp       = (u16*)  (ws + 0x6100000ull);  // 32 MiB
  u16*   resb      = (u16*)  (ws + 0x8100000ull);  // 32 MiB
  u16*   Bb        = (u16*)  (ws + 0xA100000ull);  // 32 MiB
  u16*   Cb        = (u16*)  (ws + 0xC100000ull);  // 32 MiB
  float* dtb       = (float*)(ws + 0xE100000ull);  // 1 MiB
  float* cs        = (float*)(ws + 0xE200000ull);  // 1 MiB
  float* achunk    = (float*)(ws + 0xE300000ull);  // 4 KiB

  hipFuncSetAttribute((const void*)gemm_in256,
      hipFuncAttributeMaxDynamicSharedMemorySize, 131072);
  hipFuncSetAttribute((const void*)gemm_par256,
      hipFuncAttributeMaxDynamicSharedMemorySize, 131072);

  cast_bf16<<<8192,  256, 0, stream>>>(x, xb);
  cast_bf16<<<16384, 256, 0, stream>>>(w_in, w_in_b);
  cast_bf16<<<16512, 256, 0, stream>>>(w_param, w_param_b);
  cast_bf16<<<8192,  256, 0, stream>>>(w_out, w_out_b);

  gemm_in256 <<<512, 512, 131072, stream>>>(xb, w_in_b, inp, resb);
  gemm_par256<<<528, 512, 131072, stream>>>(xb, w_param_b, dtb, Bb, Cb);
  ssd_phaseA<<<1024, 256, 0, stream>>>(dtb, Bb, inp, cs, achunk, states);
  ssd_scan<<<64, 256, 0, stream>>>(states, achunk);
  ssd_diag<<<dim3(4, 1024), 256, 0, stream>>>(Bb, Cb, inp, cs, states, resb, yb);
  gemm_out<<<dim3(16, 32), 256, 0, stream>>>(yb, w_out_b, out);
}

// Round 11
// 561.950 us; speedup vs baseline: 1.0463x; 1.0463x over previous
//
#include <hip/hip_runtime.h>
#include <math.h>

#define Q 256

typedef unsigned short u16;
typedef unsigned int u32;
typedef __attribute__((ext_vector_type(8))) short short8;
typedef __attribute__((ext_vector_type(4))) float f32x4;

__device__ __forceinline__ float bf2f(u32 u){
  union { float f; u32 i; } v; v.i = u << 16; return v.f;
}
__device__ __forceinline__ u16 f2bf(float f){
  union { float f; u32 i; } v; v.f = f;
  u32 r = (v.i + 0x7FFFu + ((v.i >> 16) & 1u)) >> 16;
  return (u16)r;
}
__device__ __forceinline__ float softplusf(float x){
  return x > 20.f ? x : log1pf(expf(x));
}
__device__ __forceinline__ float siluf(float x){
  return x / (1.f + expf(-x));
}

__device__ __forceinline__ void gload_lds16(const void* g, const void* l){
  __builtin_amdgcn_global_load_lds(
    (const __attribute__((address_space(1))) void*)(uintptr_t)g,
    (__attribute__((address_space(3))) void*)(u32)(uintptr_t)l,
    16, 0, 0);
}

__device__ __forceinline__ u32 swz_off(int row, int col2){
  return (u32)(row*128 + (col2 ^ ((row & 7) << 4)));
}
__device__ __forceinline__ short8 frag_ld(const u16* buf, int row, int kk, int lk){
  return *(const short8*)((const char*)buf + row*128 + (((kk*4 + lk) ^ (row & 7)) << 4));
}

// Fused bf16 cast of all four inputs (one launch; group = 4 floats).
__global__ __launch_bounds__(256) void cast_all(const float* __restrict__ x,
    const float* __restrict__ w_in, const float* __restrict__ w_param,
    const float* __restrict__ w_out, u16* __restrict__ xb,
    u16* __restrict__ w_in_b, u16* __restrict__ w_param_b, u16* __restrict__ w_out_b)
{
  const size_t g = (size_t)blockIdx.x * 256 + threadIdx.x;
  const float* src; u16* dst; size_t off;
  if (g < 2097152)        { src = x;       dst = xb;        off = g; }
  else if (g < 6291456)   { src = w_in;    dst = w_in_b;    off = g - 2097152; }
  else if (g < 10518528)  { src = w_param; dst = w_param_b; off = g - 6291456; }
  else                    { src = w_out;   dst = w_out_b;   off = g - 10518528; }
  const float4 v = *(const float4*)(src + off*4);
  ushort4 o;
  o.x = f2bf(v.x); o.y = f2bf(v.y); o.z = f2bf(v.z); o.w = f2bf(v.w);
  *(ushort4*)(dst + off*4) = o;
}

// ------------- TLP GEMM core: 128x256 tile, 8 waves, 2 blocks/CU -----------
// 512 thr = 8 waves (2M x 4N), per-wave 64x64 out (4x4 frags, 64 acc VGPR).
// K-slice 32; ring-2 slots of 24 KiB (48 KiB total -> 2 blocks/CU at <=128
// VGPR via __launch_bounds__(512,4)). Mechanism: cross-block TLP (m114) --
// one block's MFMA covers the other's vmcnt/barrier stalls; no intra-block
// fence tuning (6 variants all nulled at 1 block/CU).
// Slot layout: 192 LDS rows x 128 B. LDS row r packs logical rows {2r,2r+1}
// (A rows 0..127 -> r 0..63; B rows 0..255 -> r 64..191), 4 chunks each;
// phys chunk = logical ^ (r&7); gload_lds linear dest (3 chunks/thread),
// pre-swizzled global source (rule #21).
// Phase s: { stage slot (s+1)&1 ; 8 ds_read slot s&1 ; 16 MFMA ;
//            vmcnt(0) ; barrier }   (proven minimum-2-phase)
#define T256_STAGE(s_) \
  _Pragma("unroll") for (int q = 0; q < 3; q++) \
    gload_lds16(sptr[q] + (s_)*32, lds + (((s_)&1)*24576) + (q*512 + tid)*16);

#define T256_CORE(A_, B_, K_, NTN_) \
  __shared__ char lds[49152]; \
  const int tid = threadIdx.x; \
  const int nwg = gridDim.x, bid = blockIdx.x; \
  const int wg = (bid & 7) * (nwg >> 3) + (bid >> 3); \
  const int m0 = (wg / (NTN_)) * 128, n0 = (wg % (NTN_)) * 256; \
  const int w = tid >> 6, l = tid & 63; \
  const int wr = w >> 2, wc = w & 3; \
  const int lr = l & 15, lk = l >> 4; \
  const u16* sptr[3]; \
  _Pragma("unroll") for (int q = 0; q < 3; q++) { \
    const int c = q*512 + tid; \
    const int r = c >> 3; \
    const int lg = (c & 7) ^ (r & 7); \
    const int lrow2 = 2*r + (lg >> 2); \
    const int kc = lg & 3; \
    sptr[q] = (lrow2 < 128) ? ((A_) + (size_t)(m0 + lrow2)*(K_) + kc*8) \
                            : ((B_) + (size_t)(n0 + (lrow2 - 128))*(K_) + kc*8); \
  } \
  const int arow0 = wr*64 + lr; \
  const int abrow = arow0 >> 1; \
  const int abase = abrow*128 + ((((arow0 & 1)*4 + lk) ^ (abrow & 7)) << 4); \
  const int brow0 = 64 + ((wc*64 + lr) >> 1); \
  const int bbase = brow0*128 + ((((lr & 1)*4 + lk) ^ (brow0 & 7)) << 4); \
  f32x4 acc[4][4]; \
  { f32x4 z = {0.f,0.f,0.f,0.f}; \
    _Pragma("unroll") for (int m = 0; m < 4; m++) \
    _Pragma("unroll") for (int n = 0; n < 4; n++) acc[m][n] = z; } \
  T256_STAGE(0) \
  asm volatile("s_waitcnt vmcnt(0)" ::: "memory"); \
  __builtin_amdgcn_s_barrier(); \
  { const int NS = (K_)/32; \
    for (int s = 0; s < NS-1; ++s) { \
      const char* sb_ = lds + ((s & 1)*24576); \
      short8 aF[4], bF[4]; \
      T256_STAGE(s+1) \
      _Pragma("unroll") for (int m = 0; m < 4; m++) \
        aF[m] = *(const short8*)(sb_ + abase + m*1024); \
      _Pragma("unroll") for (int n = 0; n < 4; n++) \
        bF[n] = *(const short8*)(sb_ + bbase + n*1024); \
      __builtin_amdgcn_s_setprio(1); \
      _Pragma("unroll") for (int m = 0; m < 4; m++) \
      _Pragma("unroll") for (int n = 0; n < 4; n++) \
        acc[m][n] = __builtin_amdgcn_mfma_f32_16x16x32_bf16(aF[m], bF[n], acc[m][n], 0, 0, 0); \
      __builtin_amdgcn_s_setprio(0); \
      asm volatile("s_waitcnt vmcnt(0)" ::: "memory"); \
      __builtin_amdgcn_s_barrier(); \
    } \
    { const char* sb_ = lds + (((K_)/32 - 1) & 1)*24576; \
      short8 aF[4], bF[4]; \
      _Pragma("unroll") for (int m = 0; m < 4; m++) \
        aF[m] = *(const short8*)(sb_ + abase + m*1024); \
      _Pragma("unroll") for (int n = 0; n < 4; n++) \
        bF[n] = *(const short8*)(sb_ + bbase + n*1024); \
      _Pragma("unroll") for (int m = 0; m < 4; m++) \
      _Pragma("unroll") for (int n = 0; n < 4; n++) \
        acc[m][n] = __builtin_amdgcn_mfma_f32_16x16x32_bf16(aF[m], bF[n], acc[m][n], 0, 0, 0); \
    } \
  }

__global__ void __launch_bounds__(512, 4) gemm_in256(const u16* __restrict__ A,
    const u16* __restrict__ B, u16* __restrict__ inp, u16* __restrict__ resb)
{
  T256_CORE(A, B, 2048, 32)
  #pragma unroll
  for (int m = 0; m < 4; m++)
    #pragma unroll
    for (int n = 0; n < 4; n++) {
      const int col = n0 + wc*64 + n*16 + lr;
      #pragma unroll
      for (int j = 0; j < 4; j++) {
        const int row = m0 + wr*64 + m*16 + lk*4 + j;
        const u16 v = f2bf(acc[m][n][j]);
        if (col < 4096) inp[(size_t)row*4096 + col] = v;
        else            resb[(size_t)row*4096 + (col - 4096)] = v;
      }
    }
}

__global__ void __launch_bounds__(512, 4) gemm_par256(const u16* __restrict__ A,
    const u16* __restrict__ B, float* __restrict__ dtb,
    u16* __restrict__ Bb, u16* __restrict__ Cb)
{
  T256_CORE(A, B, 2048, 33)
  #pragma unroll
  for (int m = 0; m < 4; m++)
    #pragma unroll
    for (int n = 0; n < 4; n++) {
      const int col = n0 + wc*64 + n*16 + lr;
      if (col < 8256) {
        const int h = col / 129, rr = col - h*129;
        #pragma unroll
        for (int j = 0; j < 4; j++) {
          const int row = m0 + wr*64 + m*16 + lk*4 + j;
          const float v = acc[m][n][j];
          if (rr == 0)      dtb[(size_t)row*64 + h] = v;
          else if (rr < 65) Bb[((size_t)row*64 + h)*64 + (rr-1)]  = f2bf(v);
          else              Cb[((size_t)row*64 + h)*64 + (rr-65)] = f2bf(v);
        }
      }
    }
}

__global__ void __launch_bounds__(512, 4) gemm_out256(const u16* __restrict__ A,
    const u16* __restrict__ B, float* __restrict__ C)
{
  T256_CORE(A, B, 4096, 8)
  #pragma unroll
  for (int m = 0; m < 4; m++)
    #pragma unroll
    for (int n = 0; n < 4; n++) {
      const int col = n0 + wc*64 + n*16 + lr;
      #pragma unroll
      for (int j = 0; j < 4; j++)
        C[(size_t)(m0 + wr*64 + m*16 + lk*4 + j)*2048 + col] = acc[m][n][j];
    }
}

// ---------------- SSD ------------------------------------------------------
__global__ __launch_bounds__(256) void ssd_phaseA(const float* __restrict__ dtb,
    const u16* __restrict__ Bb, const u16* __restrict__ inp,
    float* __restrict__ cs_g, float* __restrict__ achunk, float* __restrict__ states_t)
{
  const int g = blockIdx.x, tid = threadIdx.x;
  const int p = g * Q + tid;
  __shared__ float sc[Q];
  __shared__ u16 sBt[64*64];
  __shared__ u16 sXt[64*64];
  sc[tid] = -softplusf(dtb[p]);
  __syncthreads();
  for (int off = 1; off < Q; off <<= 1) {
    float v = (tid >= off) ? sc[tid - off] : 0.f;
    __syncthreads();
    if (tid >= off) sc[tid] += v;
    __syncthreads();
  }
  cs_g[p] = sc[tid];
  const float cl = sc[Q-1];
  if (tid == 0) achunk[g] = expf(cl);

  const int w = tid >> 6, l = tid & 63;
  const int lrow = l & 15, lk = l >> 4;
  const int tj = tid & 63, tcb = (tid >> 6) * 16;
  f32x4 acc[4];
  { f32x4 z = {0,0,0,0}; acc[0]=z; acc[1]=z; acc[2]=z; acc[3]=z; }

  for (int js = 0; js < 4; js++) {
    __syncthreads();
    {
      const int jc = js*64 + tj;
      const float wj = expf(cl - sc[jc]);
      const size_t prow = ((size_t)g*Q + jc) * 64;
      union { uint4 v; u16 s[8]; } b0, b1, x0, x1;
      b0.v = *(const uint4*)&Bb[prow + tcb];
      b1.v = *(const uint4*)&Bb[prow + tcb + 8];
      x0.v = *(const uint4*)&inp[prow + tcb];
      x1.v = *(const uint4*)&inp[prow + tcb + 8];
      #pragma unroll
      for (int q = 0; q < 8; q++) {
        const int r0 = tcb + q, r1 = tcb + 8 + q;
        *(u16*)((char*)sBt + swz_off(r0, 2*tj)) = f2bf(wj * bf2f((u32)b0.s[q]));
        *(u16*)((char*)sBt + swz_off(r1, 2*tj)) = f2bf(wj * bf2f((u32)b1.s[q]));
        *(u16*)((char*)sXt + swz_off(r0, 2*tj)) = x0.s[q];
        *(u16*)((char*)sXt + swz_off(r1, 2*tj)) = x1.s[q];
      }
    }
    __syncthreads();
    short8 aX0 = frag_ld(sXt, w*16 + lrow, 0, lk);
    short8 aX1 = frag_ld(sXt, w*16 + lrow, 1, lk);
    #pragma unroll
    for (int n = 0; n < 4; n++) {
      short8 b0 = frag_ld(sBt, n*16 + lrow, 0, lk);
      short8 b1 = frag_ld(sBt, n*16 + lrow, 1, lk);
      acc[n] = __builtin_amdgcn_mfma_f32_16x16x32_bf16(aX0, b0, acc[n], 0, 0, 0);
      acc[n] = __builtin_amdgcn_mfma_f32_16x16x32_bf16(aX1, b1, acc[n], 0, 0, 0);
    }
  }
  #pragma unroll
  for (int reg = 0; reg < 4; reg++) {
    const int d = w*16 + lk*4 + reg;
    #pragma unroll
    for (int n = 0; n < 4; n++)
      states_t[(size_t)g*4096 + d*64 + n*16 + lrow] = acc[n][reg];
  }
}

__global__ __launch_bounds__(256) void ssd_scan(float* __restrict__ states,
    const float* __restrict__ achunk)
{
  const int n = blockIdx.x, tid = threadIdx.x;
  float S[16];
  #pragma unroll
  for (int k = 0; k < 16; k++) S[k] = 0.f;
  for (int c = 0; c < 16; c++) {
    const int g = n*16 + c;
    const float A = achunk[g];
    #pragma unroll
    for (int k = 0; k < 16; k++) {
      const size_t e = (size_t)g * 4096 + tid + k*256;
      const float st = states[e];
      states[e] = S[k];
      S[k] = fmaf(A, S[k], st);
    }
  }
}

__global__ __launch_bounds__(256) void ssd_diag(const u16* __restrict__ Bb,
    const u16* __restrict__ Cb, const u16* __restrict__ inp,
    const float* __restrict__ cs_g, const float* __restrict__ states_t,
    const u16* __restrict__ resb, u16* __restrict__ yb)
{
  const int g = blockIdx.y, it = blockIdx.x, tid = threadIdx.x;
  const int w = tid >> 6, l = tid & 63;
  const int lrow = l & 15, lk = l >> 4;
  const int p_base = g * Q;
  __shared__ u16 sC[64*64];
  __shared__ u16 sB[64*64];
  __shared__ u16 sX[64*64];
  __shared__ u16 sP[64*64];
  __shared__ float csi[64], csj[64];

  const int r = tid >> 2, c0 = (tid & 3) << 4;
  {
    const size_t prow = (size_t)(p_base + it*64 + r) * 64;
    uint4 v0 = *(const uint4*)&Cb[prow + c0];
    uint4 v1 = *(const uint4*)&Cb[prow + c0 + 8];
    *(uint4*)((char*)sC + swz_off(r, c0*2))      = v0;
    *(uint4*)((char*)sC + swz_off(r, c0*2 + 16)) = v1;
    if (tid < 64) csi[tid] = cs_g[p_base + it*64 + tid];
  }
  const int i0 = w * 16;
  const int xj = tid & 63, xdb = (tid >> 6) * 16;
  f32x4 accY[4];
  { f32x4 z = {0,0,0,0}; accY[0]=z; accY[1]=z; accY[2]=z; accY[3]=z; }

  for (int jt = 0; jt <= it; jt++) {
    __syncthreads();
    {
      const size_t prow = (size_t)(p_base + jt*64 + r) * 64;
      uint4 v0 = *(const uint4*)&Bb[prow + c0];
      uint4 v1 = *(const uint4*)&Bb[prow + c0 + 8];
      *(uint4*)((char*)sB + swz_off(r, c0*2))      = v0;
      *(uint4*)((char*)sB + swz_off(r, c0*2 + 16)) = v1;
      if (tid < 64) csj[tid] = cs_g[p_base + jt*64 + tid];
    }
    {
      const size_t prow = (size_t)(p_base + jt*64 + xj) * 64;
      union { uint4 v; u16 s[8]; } x0, x1;
      x0.v = *(const uint4*)&inp[prow + xdb];
      x1.v = *(const uint4*)&inp[prow + xdb + 8];
      #pragma unroll
      for (int q = 0; q < 8; q++) {
        *(u16*)((char*)sX + swz_off(xdb + q,     2*xj)) = x0.s[q];
        *(u16*)((char*)sX + swz_off(xdb + 8 + q, 2*xj)) = x1.s[q];
      }
    }
    __syncthreads();
    f32x4 sAcc[4];
    { f32x4 z = {0,0,0,0}; sAcc[0]=z; sAcc[1]=z; sAcc[2]=z; sAcc[3]=z; }
    {
      short8 aC0 = frag_ld(sC, i0 + lrow, 0, lk);
      short8 aC1 = frag_ld(sC, i0 + lrow, 1, lk);
      #pragma unroll
      for (int n = 0; n < 4; n++) {
        short8 b0 = frag_ld(sB, n*16 + lrow, 0, lk);
        short8 b1 = frag_ld(sB, n*16 + lrow, 1, lk);
        sAcc[n] = __builtin_amdgcn_mfma_f32_16x16x32_bf16(aC0, b0, sAcc[n], 0, 0, 0);
        sAcc[n] = __builtin_amdgcn_mfma_f32_16x16x32_bf16(aC1, b1, sAcc[n], 0, 0, 0);
      }
    }
    const bool full = (jt < it);
    #pragma unroll
    for (int n = 0; n < 4; n++) {
      const int j_l = n*16 + lrow;
      const float cj = csj[j_l];
      #pragma unroll
      for (int reg = 0; reg < 4; reg++) {
        const int i_l = i0 + lk*4 + reg;
        float s = 0.f;
        if (full || j_l <= i_l) s = sAcc[n][reg] * expf(csi[i_l] - cj);
        *(u16*)((char*)sP + swz_off(i_l, n*32 + 2*lrow)) = f2bf(s);
      }
    }
    {
      short8 aP0 = frag_ld(sP, i0 + lrow, 0, lk);
      short8 aP1 = frag_ld(sP, i0 + lrow, 1, lk);
      #pragma unroll
      for (int n = 0; n < 4; n++) {
        short8 x0f = frag_ld(sX, n*16 + lrow, 0, lk);
        short8 x1f = frag_ld(sX, n*16 + lrow, 1, lk);
        accY[n] = __builtin_amdgcn_mfma_f32_16x16x32_bf16(aP0, x0f, accY[n], 0, 0, 0);
        accY[n] = __builtin_amdgcn_mfma_f32_16x16x32_bf16(aP1, x1f, accY[n], 0, 0, 0);
      }
    }
  }
  __syncthreads();
  {
    const int d = tid & 63, sb = (tid >> 6) * 16;
    const float* srow = &states_t[(size_t)g*4096 + d*64 + sb];
    float4 f0 = *(const float4*)(srow);
    float4 f1 = *(const float4*)(srow + 4);
    float4 f2 = *(const float4*)(srow + 8);
    float4 f3 = *(const float4*)(srow + 12);
    union { uint4 v; u16 s[8]; } o0, o1;
    o0.s[0]=f2bf(f0.x); o0.s[1]=f2bf(f0.y); o0.s[2]=f2bf(f0.z); o0.s[3]=f2bf(f0.w);
    o0.s[4]=f2bf(f1.x); o0.s[5]=f2bf(f1.y); o0.s[6]=f2bf(f1.z); o0.s[7]=f2bf(f1.w);
    o1.s[0]=f2bf(f2.x); o1.s[1]=f2bf(f2.y); o1.s[2]=f2bf(f2.z); o1.s[3]=f2bf(f2.w);
    o1.s[4]=f2bf(f3.x); o1.s[5]=f2bf(f3.y); o1.s[6]=f2bf(f3.z); o1.s[7]=f2bf(f3.w);
    *(uint4*)((char*)sB + swz_off(d, sb*2))      = o0.v;
    *(uint4*)((char*)sB + swz_off(d, sb*2 + 16)) = o1.v;
  }
  __syncthreads();
  f32x4 accI[4];
  { f32x4 z = {0,0,0,0}; accI[0]=z; accI[1]=z; accI[2]=z; accI[3]=z; }
  {
    short8 aC0 = frag_ld(sC, i0 + lrow, 0, lk);
    short8 aC1 = frag_ld(sC, i0 + lrow, 1, lk);
    #pragma unroll
    for (int n = 0; n < 4; n++) {
      short8 s0 = frag_ld(sB, n*16 + lrow, 0, lk);
      short8 s1 = frag_ld(sB, n*16 + lrow, 1, lk);
      accI[n] = __builtin_amdgcn_mfma_f32_16x16x32_bf16(aC0, s0, accI[n], 0, 0, 0);
      accI[n] = __builtin_amdgcn_mfma_f32_16x16x32_bf16(aC1, s1, accI[n], 0, 0, 0);
    }
  }
  #pragma unroll
  for (int reg = 0; reg < 4; reg++) {
    const int i_l = i0 + lk*4 + reg;
    const float ei = expf(csi[i_l]);
    const size_t prow = (size_t)(p_base + it*64 + i_l) * 64;
    #pragma unroll
    for (int n = 0; n < 4; n++) {
      const int d = n*16 + lrow;
      const float yv = accY[n][reg] + ei * accI[n][reg];
      const float rv = bf2f((u32)resb[prow + d]);
      yb[prow + d] = f2bf(yv * siluf(rv));
    }
  }
}

extern "C" void kernel_launch(void* const* d_in, const int* in_sizes, int n_in,
                              void* d_out, int out_size, void* d_ws, size_t ws_size,
                              hipStream_t stream)
{
  const float* x       = (const float*)d_in[0];
  const float* w_in    = (const float*)d_in[1];
  const float* w_param = (const float*)d_in[2];
  const float* w_out   = (const float*)d_in[3];
  float* out = (float*)d_out;
  char* ws = (char*)d_ws;

  float* states    = (float*)(ws);                 // 16 MiB (aliases xb)
  u16*   xb        = (u16*)  (ws);                 // 16 MiB
  u16*   yb        = (u16*)  (ws + 0x1000000ull);  // 32 MiB (aliases w_in_b)
  u16*   w_in_b    = (u16*)  (ws + 0x1000000ull);  // 32 MiB
  u16*   w_param_b = (u16*)  (ws + 0x3000000ull);  // 8448*2048*2 = 33 MiB (pad rows)
  u16*   w_out_b   = (u16*)  (ws + 0x5100000ull);  // 16 MiB
  u16*   inp       = (u16*)  (ws + 0x6100000ull);  // 32 MiB
  u16*   resb      = (u16*)  (ws + 0x8100000ull);  // 32 MiB
  u16*   Bb        = (u16*)  (ws + 0xA100000ull);  // 32 MiB
  u16*   Cb        = (u16*)  (ws + 0xC100000ull);  // 32 MiB
  float* dtb       = (float*)(ws + 0xE100000ull);  // 1 MiB
  float* cs        = (float*)(ws + 0xE200000ull);  // 1 MiB
  float* achunk    = (float*)(ws + 0xE300000ull);  // 4 KiB

  cast_all<<<49280, 256, 0, stream>>>(x, w_in, w_param, w_out,
                                      xb, w_in_b, w_param_b, w_out_b);

  gemm_in256 <<<1024, 512, 0, stream>>>(xb, w_in_b, inp, resb);
  gemm_par256<<<1056, 512, 0, stream>>>(xb, w_param_b, dtb, Bb, Cb);
  ssd_phaseA<<<1024, 256, 0, stream>>>(dtb, Bb, inp, cs, achunk, states);
  ssd_scan<<<64, 256, 0, stream>>>(states, achunk);
  ssd_diag<<<dim3(4, 1024), 256, 0, stream>>>(Bb, Cb, inp, cs, states, resb, yb);
  gemm_out256<<<256, 512, 0, stream>>>(yb, w_out_b, out);
}

// Round 12
// 552.714 us; speedup vs baseline: 1.0638x; 1.0167x over previous
//
#include <hip/hip_runtime.h>
#include <math.h>

#define Q 256

typedef unsigned short u16;
typedef unsigned int u32;
typedef __attribute__((ext_vector_type(8))) short short8;
typedef __attribute__((ext_vector_type(4))) float f32x4;

__device__ __forceinline__ float bf2f(u32 u){
  union { float f; u32 i; } v; v.i = u << 16; return v.f;
}
__device__ __forceinline__ u16 f2bf(float f){
  union { float f; u32 i; } v; v.f = f;
  u32 r = (v.i + 0x7FFFu + ((v.i >> 16) & 1u)) >> 16;
  return (u16)r;
}
__device__ __forceinline__ float softplusf(float x){
  return x > 20.f ? x : log1pf(expf(x));
}
__device__ __forceinline__ float siluf(float x){
  return x / (1.f + expf(-x));
}

__device__ __forceinline__ void gload_lds16(const void* g, const void* l){
  __builtin_amdgcn_global_load_lds(
    (const __attribute__((address_space(1))) void*)(uintptr_t)g,
    (__attribute__((address_space(3))) void*)(u32)(uintptr_t)l,
    16, 0, 0);
}

__device__ __forceinline__ u32 swz_off(int row, int col2){
  return (u32)(row*128 + (col2 ^ ((row & 7) << 4)));
}
__device__ __forceinline__ short8 frag_ld(const u16* buf, int row, int kk, int lk){
  return *(const short8*)((const char*)buf + row*128 + (((kk*4 + lk) ^ (row & 7)) << 4));
}

// Fused bf16 cast of all four inputs (one launch; group = 4 floats).
__global__ __launch_bounds__(256) void cast_all(const float* __restrict__ x,
    const float* __restrict__ w_in, const float* __restrict__ w_param,
    const float* __restrict__ w_out, u16* __restrict__ xb,
    u16* __restrict__ w_in_b, u16* __restrict__ w_param_b, u16* __restrict__ w_out_b)
{
  const size_t g = (size_t)blockIdx.x * 256 + threadIdx.x;
  const float* src; u16* dst; size_t off;
  if (g < 2097152)        { src = x;       dst = xb;        off = g; }
  else if (g < 6291456)   { src = w_in;    dst = w_in_b;    off = g - 2097152; }
  else if (g < 10518528)  { src = w_param; dst = w_param_b; off = g - 6291456; }
  else                    { src = w_out;   dst = w_out_b;   off = g - 10518528; }
  const float4 v = *(const float4*)(src + off*4);
  ushort4 o;
  o.x = f2bf(v.x); o.y = f2bf(v.y); o.z = f2bf(v.z); o.w = f2bf(v.w);
  *(ushort4*)(dst + off*4) = o;
}

// ------------- TLP GEMM core: 128x256 tile, 8 waves, 2 blocks/CU -----------
// (unchanged from round 11: minimum-2-phase + cross-block TLP; 0 bank conf.)
#define T256_STAGE(s_) \
  _Pragma("unroll") for (int q = 0; q < 3; q++) \
    gload_lds16(sptr[q] + (s_)*32, lds + (((s_)&1)*24576) + (q*512 + tid)*16);

#define T256_CORE(A_, B_, K_, NTN_) \
  __shared__ char lds[49152]; \
  const int tid = threadIdx.x; \
  const int nwg = gridDim.x, bid = blockIdx.x; \
  const int wg = (bid & 7) * (nwg >> 3) + (bid >> 3); \
  const int m0 = (wg / (NTN_)) * 128, n0 = (wg % (NTN_)) * 256; \
  const int w = tid >> 6, l = tid & 63; \
  const int wr = w >> 2, wc = w & 3; \
  const int lr = l & 15, lk = l >> 4; \
  const u16* sptr[3]; \
  _Pragma("unroll") for (int q = 0; q < 3; q++) { \
    const int c = q*512 + tid; \
    const int r = c >> 3; \
    const int lg = (c & 7) ^ (r & 7); \
    const int lrow2 = 2*r + (lg >> 2); \
    const int kc = lg & 3; \
    sptr[q] = (lrow2 < 128) ? ((A_) + (size_t)(m0 + lrow2)*(K_) + kc*8) \
                            : ((B_) + (size_t)(n0 + (lrow2 - 128))*(K_) + kc*8); \
  } \
  const int arow0 = wr*64 + lr; \
  const int abrow = arow0 >> 1; \
  const int abase = abrow*128 + ((((arow0 & 1)*4 + lk) ^ (abrow & 7)) << 4); \
  const int brow0 = 64 + ((wc*64 + lr) >> 1); \
  const int bbase = brow0*128 + ((((lr & 1)*4 + lk) ^ (brow0 & 7)) << 4); \
  f32x4 acc[4][4]; \
  { f32x4 z = {0.f,0.f,0.f,0.f}; \
    _Pragma("unroll") for (int m = 0; m < 4; m++) \
    _Pragma("unroll") for (int n = 0; n < 4; n++) acc[m][n] = z; } \
  T256_STAGE(0) \
  asm volatile("s_waitcnt vmcnt(0)" ::: "memory"); \
  __builtin_amdgcn_s_barrier(); \
  { const int NS = (K_)/32; \
    for (int s = 0; s < NS-1; ++s) { \
      const char* sb_ = lds + ((s & 1)*24576); \
      short8 aF[4], bF[4]; \
      T256_STAGE(s+1) \
      _Pragma("unroll") for (int m = 0; m < 4; m++) \
        aF[m] = *(const short8*)(sb_ + abase + m*1024); \
      _Pragma("unroll") for (int n = 0; n < 4; n++) \
        bF[n] = *(const short8*)(sb_ + bbase + n*1024); \
      __builtin_amdgcn_s_setprio(1); \
      _Pragma("unroll") for (int m = 0; m < 4; m++) \
      _Pragma("unroll") for (int n = 0; n < 4; n++) \
        acc[m][n] = __builtin_amdgcn_mfma_f32_16x16x32_bf16(aF[m], bF[n], acc[m][n], 0, 0, 0); \
      __builtin_amdgcn_s_setprio(0); \
      asm volatile("s_waitcnt vmcnt(0)" ::: "memory"); \
      __builtin_amdgcn_s_barrier(); \
    } \
    { const char* sb_ = lds + (((K_)/32 - 1) & 1)*24576; \
      short8 aF[4], bF[4]; \
      _Pragma("unroll") for (int m = 0; m < 4; m++) \
        aF[m] = *(const short8*)(sb_ + abase + m*1024); \
      _Pragma("unroll") for (int n = 0; n < 4; n++) \
        bF[n] = *(const short8*)(sb_ + bbase + n*1024); \
      _Pragma("unroll") for (int m = 0; m < 4; m++) \
      _Pragma("unroll") for (int n = 0; n < 4; n++) \
        acc[m][n] = __builtin_amdgcn_mfma_f32_16x16x32_bf16(aF[m], bF[n], acc[m][n], 0, 0, 0); \
    } \
  }

// ------------- T128 core: 128x128 tile, 8 waves (2Mx4N of 64x32) -----------
// Same layout family as T256 (2 logical rows per 128-B LDS row, XOR chunk
// swizzle, gload_lds linear dest + pre-swizzled source); slot 16 KiB,
// 2 loads/thread/slice; 2 blocks/CU. Used where grid shape needs 128-wide
// N-tiles (gemm_out: 32x16=512 blocks = exact capacity; par_tail: 32 blocks).
#define T128_STAGE(s_) \
  _Pragma("unroll") for (int q = 0; q < 2; q++) \
    gload_lds16(sptr[q] + (s_)*32, lds + (((s_)&1)*16384) + (q*512 + tid)*16);

#define T128_CORE(A_, B_, K_, NTN_) \
  __shared__ char lds[32768]; \
  const int tid = threadIdx.x; \
  const int nwg = gridDim.x, bid = blockIdx.x; \
  const int wg = (nwg >= 8) ? ((bid & 7) * (nwg >> 3) + (bid >> 3)) : bid; \
  const int m0 = (wg / (NTN_)) * 128, n0 = (wg % (NTN_)) * 128; \
  const int w = tid >> 6, l = tid & 63; \
  const int wr = w >> 2, wc = w & 3; \
  const int lr = l & 15, lk = l >> 4; \
  const u16* sptr[2]; \
  _Pragma("unroll") for (int q = 0; q < 2; q++) { \
    const int c = q*512 + tid; \
    const int r = c >> 3; \
    const int lg = (c & 7) ^ (r & 7); \
    const int lrow2 = 2*r + (lg >> 2); \
    const int kc = lg & 3; \
    sptr[q] = (lrow2 < 128) ? ((A_) + (size_t)(m0 + lrow2)*(K_) + kc*8) \
                            : ((B_) + (size_t)(n0 + (lrow2 - 128))*(K_) + kc*8); \
  } \
  const int arow0 = wr*64 + lr; \
  const int abrow = arow0 >> 1; \
  const int abase = abrow*128 + ((((arow0 & 1)*4 + lk) ^ (abrow & 7)) << 4); \
  const int brow0 = 64 + ((wc*32 + lr) >> 1); \
  const int bbase = brow0*128 + ((((lr & 1)*4 + lk) ^ (brow0 & 7)) << 4); \
  f32x4 acc[4][2]; \
  { f32x4 z = {0.f,0.f,0.f,0.f}; \
    _Pragma("unroll") for (int m = 0; m < 4; m++) \
    _Pragma("unroll") for (int n = 0; n < 2; n++) acc[m][n] = z; } \
  T128_STAGE(0) \
  asm volatile("s_waitcnt vmcnt(0)" ::: "memory"); \
  __builtin_amdgcn_s_barrier(); \
  { const int NS = (K_)/32; \
    for (int s = 0; s < NS-1; ++s) { \
      const char* sb_ = lds + ((s & 1)*16384); \
      short8 aF[4], bF[2]; \
      T128_STAGE(s+1) \
      _Pragma("unroll") for (int m = 0; m < 4; m++) \
        aF[m] = *(const short8*)(sb_ + abase + m*1024); \
      _Pragma("unroll") for (int n = 0; n < 2; n++) \
        bF[n] = *(const short8*)(sb_ + bbase + n*1024); \
      __builtin_amdgcn_s_setprio(1); \
      _Pragma("unroll") for (int m = 0; m < 4; m++) \
      _Pragma("unroll") for (int n = 0; n < 2; n++) \
        acc[m][n] = __builtin_amdgcn_mfma_f32_16x16x32_bf16(aF[m], bF[n], acc[m][n], 0, 0, 0); \
      __builtin_amdgcn_s_setprio(0); \
      asm volatile("s_waitcnt vmcnt(0)" ::: "memory"); \
      __builtin_amdgcn_s_barrier(); \
    } \
    { const char* sb_ = lds + (((K_)/32 - 1) & 1)*16384; \
      short8 aF[4], bF[2]; \
      _Pragma("unroll") for (int m = 0; m < 4; m++) \
        aF[m] = *(const short8*)(sb_ + abase + m*1024); \
      _Pragma("unroll") for (int n = 0; n < 2; n++) \
        bF[n] = *(const short8*)(sb_ + bbase + n*1024); \
      _Pragma("unroll") for (int m = 0; m < 4; m++) \
      _Pragma("unroll") for (int n = 0; n < 2; n++) \
        acc[m][n] = __builtin_amdgcn_mfma_f32_16x16x32_bf16(aF[m], bF[n], acc[m][n], 0, 0, 0); \
    } \
  }

__global__ void __launch_bounds__(512, 4) gemm_in256(const u16* __restrict__ A,
    const u16* __restrict__ B, u16* __restrict__ inp, u16* __restrict__ resb)
{
  T256_CORE(A, B, 2048, 32)
  #pragma unroll
  for (int m = 0; m < 4; m++)
    #pragma unroll
    for (int n = 0; n < 4; n++) {
      const int col = n0 + wc*64 + n*16 + lr;
      #pragma unroll
      for (int j = 0; j < 4; j++) {
        const int row = m0 + wr*64 + m*16 + lk*4 + j;
        const u16 v = f2bf(acc[m][n][j]);
        if (col < 4096) inp[(size_t)row*4096 + col] = v;
        else            resb[(size_t)row*4096 + (col - 4096)] = v;
      }
    }
}

// main param GEMM: cols 0..8191 (32 col-tiles -> grid 1024 = 2 full rounds)
__global__ void __launch_bounds__(512, 4) gemm_par256(const u16* __restrict__ A,
    const u16* __restrict__ B, float* __restrict__ dtb,
    u16* __restrict__ Bb, u16* __restrict__ Cb)
{
  T256_CORE(A, B, 2048, 32)
  #pragma unroll
  for (int m = 0; m < 4; m++)
    #pragma unroll
    for (int n = 0; n < 4; n++) {
      const int col = n0 + wc*64 + n*16 + lr;
      const int h = col / 129, rr = col - h*129;
      #pragma unroll
      for (int j = 0; j < 4; j++) {
        const int row = m0 + wr*64 + m*16 + lk*4 + j;
        const float v = acc[m][n][j];
        if (rr == 0)      dtb[(size_t)row*64 + h] = v;
        else if (rr < 65) Bb[((size_t)row*64 + h)*64 + (rr-1)]  = f2bf(v);
        else              Cb[((size_t)row*64 + h)*64 + (rr-65)] = f2bf(v);
      }
    }
}

// param tail: cols 8192..8255 (quarter tile) via 32 cheap 128x128 blocks.
// B pre-offset by 8192 rows; cols >= 8256 computed on pad rows, never stored.
__global__ void __launch_bounds__(512, 4) gemm_par_tail(const u16* __restrict__ A,
    const u16* __restrict__ B, float* __restrict__ dtb,
    u16* __restrict__ Bb, u16* __restrict__ Cb)
{
  T128_CORE(A, B, 2048, 1)
  #pragma unroll
  for (int m = 0; m < 4; m++)
    #pragma unroll
    for (int n = 0; n < 2; n++) {
      const int col = 8192 + n0 + wc*32 + n*16 + lr;
      if (col < 8256) {
        const int h = col / 129, rr = col - h*129;
        #pragma unroll
        for (int j = 0; j < 4; j++) {
          const int row = m0 + wr*64 + m*16 + lk*4 + j;
          const float v = acc[m][n][j];
          if (rr == 0)      dtb[(size_t)row*64 + h] = v;
          else if (rr < 65) Bb[((size_t)row*64 + h)*64 + (rr-1)]  = f2bf(v);
          else              Cb[((size_t)row*64 + h)*64 + (rr-65)] = f2bf(v);
        }
      }
    }
}

// out-proj: 128x128 tiles -> grid 32x16 = 512 = exactly 2 blocks/CU capacity.
__global__ void __launch_bounds__(512, 4) gemm_out128(const u16* __restrict__ A,
    const u16* __restrict__ B, float* __restrict__ C)
{
  T128_CORE(A, B, 4096, 16)
  #pragma unroll
  for (int m = 0; m < 4; m++)
    #pragma unroll
    for (int n = 0; n < 2; n++) {
      const int col = n0 + wc*32 + n*16 + lr;
      #pragma unroll
      for (int j = 0; j < 4; j++)
        C[(size_t)(m0 + wr*64 + m*16 + lk*4 + j)*2048 + col] = acc[m][n][j];
    }
}

// ---------------- SSD ------------------------------------------------------
__global__ __launch_bounds__(256) void ssd_phaseA(const float* __restrict__ dtb,
    const u16* __restrict__ Bb, const u16* __restrict__ inp,
    float* __restrict__ cs_g, float* __restrict__ achunk, float* __restrict__ states_t)
{
  const int g = blockIdx.x, tid = threadIdx.x;
  const int p = g * Q + tid;
  __shared__ float sc[Q];
  __shared__ u16 sBt[64*64];
  __shared__ u16 sXt[64*64];
  sc[tid] = -softplusf(dtb[p]);
  __syncthreads();
  for (int off = 1; off < Q; off <<= 1) {
    float v = (tid >= off) ? sc[tid - off] : 0.f;
    __syncthreads();
    if (tid >= off) sc[tid] += v;
    __syncthreads();
  }
  cs_g[p] = sc[tid];
  const float cl = sc[Q-1];
  if (tid == 0) achunk[g] = expf(cl);

  const int w = tid >> 6, l = tid & 63;
  const int lrow = l & 15, lk = l >> 4;
  const int tj = tid & 63, tcb = (tid >> 6) * 16;
  f32x4 acc[4];
  { f32x4 z = {0,0,0,0}; acc[0]=z; acc[1]=z; acc[2]=z; acc[3]=z; }

  for (int js = 0; js < 4; js++) {
    __syncthreads();
    {
      const int jc = js*64 + tj;
      const float wj = expf(cl - sc[jc]);
      const size_t prow = ((size_t)g*Q + jc) * 64;
      union { uint4 v; u16 s[8]; } b0, b1, x0, x1;
      b0.v = *(const uint4*)&Bb[prow + tcb];
      b1.v = *(const uint4*)&Bb[prow + tcb + 8];
      x0.v = *(const uint4*)&inp[prow + tcb];
      x1.v = *(const uint4*)&inp[prow + tcb + 8];
      #pragma unroll
      for (int q = 0; q < 8; q++) {
        const int r0 = tcb + q, r1 = tcb + 8 + q;
        *(u16*)((char*)sBt + swz_off(r0, 2*tj)) = f2bf(wj * bf2f((u32)b0.s[q]));
        *(u16*)((char*)sBt + swz_off(r1, 2*tj)) = f2bf(wj * bf2f((u32)b1.s[q]));
        *(u16*)((char*)sXt + swz_off(r0, 2*tj)) = x0.s[q];
        *(u16*)((char*)sXt + swz_off(r1, 2*tj)) = x1.s[q];
      }
    }
    __syncthreads();
    short8 aX0 = frag_ld(sXt, w*16 + lrow, 0, lk);
    short8 aX1 = frag_ld(sXt, w*16 + lrow, 1, lk);
    #pragma unroll
    for (int n = 0; n < 4; n++) {
      short8 b0 = frag_ld(sBt, n*16 + lrow, 0, lk);
      short8 b1 = frag_ld(sBt, n*16 + lrow, 1, lk);
      acc[n] = __builtin_amdgcn_mfma_f32_16x16x32_bf16(aX0, b0, acc[n], 0, 0, 0);
      acc[n] = __builtin_amdgcn_mfma_f32_16x16x32_bf16(aX1, b1, acc[n], 0, 0, 0);
    }
  }
  #pragma unroll
  for (int reg = 0; reg < 4; reg++) {
    const int d = w*16 + lk*4 + reg;
    #pragma unroll
    for (int n = 0; n < 4; n++)
      states_t[(size_t)g*4096 + d*64 + n*16 + lrow] = acc[n][reg];
  }
}

__global__ __launch_bounds__(256) void ssd_scan(float* __restrict__ states,
    const float* __restrict__ achunk)
{
  const int n = blockIdx.x, tid = threadIdx.x;
  float S[16];
  #pragma unroll
  for (int k = 0; k < 16; k++) S[k] = 0.f;
  for (int c = 0; c < 16; c++) {
    const int g = n*16 + c;
    const float A = achunk[g];
    #pragma unroll
    for (int k = 0; k < 16; k++) {
      const size_t e = (size_t)g * 4096 + tid + k*256;
      const float st = states[e];
      states[e] = S[k];
      S[k] = fmaf(A, S[k], st);
    }
  }
}

__global__ __launch_bounds__(256) void ssd_diag(const u16* __restrict__ Bb,
    const u16* __restrict__ Cb, const u16* __restrict__ inp,
    const float* __restrict__ cs_g, const float* __restrict__ states_t,
    const u16* __restrict__ resb, u16* __restrict__ yb)
{
  const int g = blockIdx.y, it = blockIdx.x, tid = threadIdx.x;
  const int w = tid >> 6, l = tid & 63;
  const int lrow = l & 15, lk = l >> 4;
  const int p_base = g * Q;
  __shared__ u16 sC[64*64];
  __shared__ u16 sB[64*64];
  __shared__ u16 sX[64*64];
  __shared__ u16 sP[64*64];
  __shared__ float csi[64], csj[64];

  const int r = tid >> 2, c0 = (tid & 3) << 4;
  {
    const size_t prow = (size_t)(p_base + it*64 + r) * 64;
    uint4 v0 = *(const uint4*)&Cb[prow + c0];
    uint4 v1 = *(const uint4*)&Cb[prow + c0 + 8];
    *(uint4*)((char*)sC + swz_off(r, c0*2))      = v0;
    *(uint4*)((char*)sC + swz_off(r, c0*2 + 16)) = v1;
    if (tid < 64) csi[tid] = cs_g[p_base + it*64 + tid];
  }
  const int i0 = w * 16;
  const int xj = tid & 63, xdb = (tid >> 6) * 16;
  f32x4 accY[4];
  { f32x4 z = {0,0,0,0}; accY[0]=z; accY[1]=z; accY[2]=z; accY[3]=z; }

  for (int jt = 0; jt <= it; jt++) {
    __syncthreads();
    {
      const size_t prow = (size_t)(p_base + jt*64 + r) * 64;
      uint4 v0 = *(const uint4*)&Bb[prow + c0];
      uint4 v1 = *(const uint4*)&Bb[prow + c0 + 8];
      *(uint4*)((char*)sB + swz_off(r, c0*2))      = v0;
      *(uint4*)((char*)sB + swz_off(r, c0*2 + 16)) = v1;
      if (tid < 64) csj[tid] = cs_g[p_base + jt*64 + tid];
    }
    {
      const size_t prow = (size_t)(p_base + jt*64 + xj) * 64;
      union { uint4 v; u16 s[8]; } x0, x1;
      x0.v = *(const uint4*)&inp[prow + xdb];
      x1.v = *(const uint4*)&inp[prow + xdb + 8];
      #pragma unroll
      for (int q = 0; q < 8; q++) {
        *(u16*)((char*)sX + swz_off(xdb + q,     2*xj)) = x0.s[q];
        *(u16*)((char*)sX + swz_off(xdb + 8 + q, 2*xj)) = x1.s[q];
      }
    }
    __syncthreads();
    f32x4 sAcc[4];
    { f32x4 z = {0,0,0,0}; sAcc[0]=z; sAcc[1]=z; sAcc[2]=z; sAcc[3]=z; }
    {
      short8 aC0 = frag_ld(sC, i0 + lrow, 0, lk);
      short8 aC1 = frag_ld(sC, i0 + lrow, 1, lk);
      #pragma unroll
      for (int n = 0; n < 4; n++) {
        short8 b0 = frag_ld(sB, n*16 + lrow, 0, lk);
        short8 b1 = frag_ld(sB, n*16 + lrow, 1, lk);
        sAcc[n] = __builtin_amdgcn_mfma_f32_16x16x32_bf16(aC0, b0, sAcc[n], 0, 0, 0);
        sAcc[n] = __builtin_amdgcn_mfma_f32_16x16x32_bf16(aC1, b1, sAcc[n], 0, 0, 0);
      }
    }
    const bool full = (jt < it);
    #pragma unroll
    for (int n = 0; n < 4; n++) {
      const int j_l = n*16 + lrow;
      const float cj = csj[j_l];
      #pragma unroll
      for (int reg = 0; reg < 4; reg++) {
        const int i_l = i0 + lk*4 + reg;
        float s = 0.f;
        if (full || j_l <= i_l) s = sAcc[n][reg] * expf(csi[i_l] - cj);
        *(u16*)((char*)sP + swz_off(i_l, n*32 + 2*lrow)) = f2bf(s);
      }
    }
    {
      short8 aP0 = frag_ld(sP, i0 + lrow, 0, lk);
      short8 aP1 = frag_ld(sP, i0 + lrow, 1, lk);
      #pragma unroll
      for (int n = 0; n < 4; n++) {
        short8 x0f = frag_ld(sX, n*16 + lrow, 0, lk);
        short8 x1f = frag_ld(sX, n*16 + lrow, 1, lk);
        accY[n] = __builtin_amdgcn_mfma_f32_16x16x32_bf16(aP0, x0f, accY[n], 0, 0, 0);
        accY[n] = __builtin_amdgcn_mfma_f32_16x16x32_bf16(aP1, x1f, accY[n], 0, 0, 0);
      }
    }
  }
  __syncthreads();
  {
    const int d = tid & 63, sb = (tid >> 6) * 16;
    const float* srow = &states_t[(size_t)g*4096 + d*64 + sb];
    float4 f0 = *(const float4*)(srow);
    float4 f1 = *(const float4*)(srow + 4);
    float4 f2 = *(const float4*)(srow + 8);
    float4 f3 = *(const float4*)(srow + 12);
    union { uint4 v; u16 s[8]; } o0, o1;
    o0.s[0]=f2bf(f0.x); o0.s[1]=f2bf(f0.y); o0.s[2]=f2bf(f0.z); o0.s[3]=f2bf(f0.w);
    o0.s[4]=f2bf(f1.x); o0.s[5]=f2bf(f1.y); o0.s[6]=f2bf(f1.z); o0.s[7]=f2bf(f1.w);
    o1.s[0]=f2bf(f2.x); o1.s[1]=f2bf(f2.y); o1.s[2]=f2bf(f2.z); o1.s[3]=f2bf(f2.w);
    o1.s[4]=f2bf(f3.x); o1.s[5]=f2bf(f3.y); o1.s[6]=f2bf(f3.z); o1.s[7]=f2bf(f3.w);
    *(uint4*)((char*)sB + swz_off(d, sb*2))      = o0.v;
    *(uint4*)((char*)sB + swz_off(d, sb*2 + 16)) = o1.v;
  }
  __syncthreads();
  f32x4 accI[4];
  { f32x4 z = {0,0,0,0}; accI[0]=z; accI[1]=z; accI[2]=z; accI[3]=z; }
  {
    short8 aC0 = frag_ld(sC, i0 + lrow, 0, lk);
    short8 aC1 = frag_ld(sC, i0 + lrow, 1, lk);
    #pragma unroll
    for (int n = 0; n < 4; n++) {
      short8 s0 = frag_ld(sB, n*16 + lrow, 0, lk);
      short8 s1 = frag_ld(sB, n*16 + lrow, 1, lk);
      accI[n] = __builtin_amdgcn_mfma_f32_16x16x32_bf16(aC0, s0, accI[n], 0, 0, 0);
      accI[n] = __builtin_amdgcn_mfma_f32_16x16x32_bf16(aC1, s1, accI[n], 0, 0, 0);
    }
  }
  #pragma unroll
  for (int reg = 0; reg < 4; reg++) {
    const int i_l = i0 + lk*4 + reg;
    const float ei = expf(csi[i_l]);
    const size_t prow = (size_t)(p_base + it*64 + i_l) * 64;
    #pragma unroll
    for (int n = 0; n < 4; n++) {
      const int d = n*16 + lrow;
      const float yv = accY[n][reg] + ei * accI[n][reg];
      const float rv = bf2f((u32)resb[prow + d]);
      yb[prow + d] = f2bf(yv * siluf(rv));
    }
  }
}

extern "C" void kernel_launch(void* const* d_in, const int* in_sizes, int n_in,
                              void* d_out, int out_size, void* d_ws, size_t ws_size,
                              hipStream_t stream)
{
  const float* x       = (const float*)d_in[0];
  const float* w_in    = (const float*)d_in[1];
  const float* w_param = (const float*)d_in[2];
  const float* w_out   = (const float*)d_in[3];
  float* out = (float*)d_out;
  char* ws = (char*)d_ws;

  float* states    = (float*)(ws);                 // 16 MiB (aliases xb)
  u16*   xb        = (u16*)  (ws);                 // 16 MiB
  u16*   yb        = (u16*)  (ws + 0x1000000ull);  // 32 MiB (aliases w_in_b)
  u16*   w_in_b    = (u16*)  (ws + 0x1000000ull);  // 32 MiB
  u16*   w_param_b = (u16*)  (ws + 0x3000000ull);  // 8448*2048*2 = 33 MiB (pad rows)
  u16*   w_out_b   = (u16*)  (ws + 0x5100000ull);  // 16 MiB
  u16*   inp       = (u16*)  (ws + 0x6100000ull);  // 32 MiB
  u16*   resb      = (u16*)  (ws + 0x8100000ull);  // 32 MiB
  u16*   Bb        = (u16*)  (ws + 0xA100000ull);  // 32 MiB
  u16*   Cb        = (u16*)  (ws + 0xC100000ull);  // 32 MiB
  float* dtb       = (float*)(ws + 0xE100000ull);  // 1 MiB
  float* cs        = (float*)(ws + 0xE200000ull);  // 1 MiB
  float* achunk    = (float*)(ws + 0xE300000ull);  // 4 KiB

  cast_all<<<49280, 256, 0, stream>>>(x, w_in, w_param, w_out,
                                      xb, w_in_b, w_param_b, w_out_b);

  gemm_in256  <<<1024, 512, 0, stream>>>(xb, w_in_b, inp, resb);
  gemm_par256 <<<1024, 512, 0, stream>>>(xb, w_param_b, dtb, Bb, Cb);
  gemm_par_tail<<<32,  512, 0, stream>>>(xb, w_param_b + (size_t)8192*2048, dtb, Bb, Cb);
  ssd_phaseA<<<1024, 256, 0, stream>>>(dtb, Bb, inp, cs, achunk, states);
  ssd_scan<<<64, 256, 0, stream>>>(states, achunk);
  ssd_diag<<<dim3(4, 1024), 256, 0, stream>>>(Bb, Cb, inp, cs, states, resb, yb);
  gemm_out128<<<512, 512, 0, stream>>>(yb, w_out_b, out);
}